// Round 1
// baseline (675.811 us; speedup 1.0000x reference)
//
#include <hip/hip_runtime.h>
#include <cstddef>

#define BD 128
#define NS 8
#define ROWS 16
#define BLOCK 256

__device__ __forceinline__ float sigm(float x) { return 1.0f / (1.0f + __expf(-x)); }

__global__ __launch_bounds__(BLOCK, 2)
void sbcore_kernel(
    const float* __restrict__ g_signal, const float* __restrict__ g_prev,
    const float* __restrict__ g_hidden, const float* __restrict__ g_keys,
    const float* __restrict__ g_vals, const float* __restrict__ g_str,
    const float* __restrict__ g_age,
    const float* __restrict__ w_rq, const float* __restrict__ w_mix,
    const float* __restrict__ b_mix, const float* __restrict__ w_key,
    const float* __restrict__ b_key, const float* __restrict__ w_val,
    const float* __restrict__ b_val, const float* __restrict__ w_wr,
    const float* __restrict__ b_wr, const float* __restrict__ w_pe,
    const float* __restrict__ b_pe, const float* __restrict__ w_mg,
    const float* __restrict__ b_mg,
    float* __restrict__ o_read, float* __restrict__ o_keys,
    float* __restrict__ o_vals, float* __restrict__ o_str,
    float* __restrict__ o_age)
{
    __shared__ float sig_s[ROWS][BD];
    __shared__ float prv_s[ROWS][BD];
    __shared__ float hid_s[ROWS][BD];
    __shared__ float q_s[ROWS][BD];
    __shared__ float ck_s[ROWS][BD];
    __shared__ float cv_s[ROWS][BD];
    __shared__ float wmix_s[2*BD], wwr_s[2*BD], wpe_s[2*BD], wmg_s[2*BD];
    __shared__ float str_s[ROWS*NS], age_s[ROWS*NS];
    __shared__ float red_s[4][8][2];
    __shared__ float ckinv_s[ROWS];

    const int tid = threadIdx.x;
    const int row0 = blockIdx.x * ROWS;

    // ---- phase 0: cooperative staging ----
    for (int i = tid; i < ROWS*BD; i += BLOCK) {
        int r = i >> 7, dd = i & (BD-1);
        size_t g = (size_t)(row0 + r) * BD + dd;
        sig_s[r][dd] = g_signal[g];
        prv_s[r][dd] = g_prev[g];
        hid_s[r][dd] = g_hidden[g];
    }
    if (tid < ROWS*NS) {
        str_s[tid] = g_str[(size_t)row0*NS + tid];
        age_s[tid] = g_age[(size_t)row0*NS + tid];
    }
    wmix_s[tid] = w_mix[tid];
    wwr_s[tid]  = w_wr[tid];
    wpe_s[tid]  = w_pe[tid];
    wmg_s[tid]  = w_mg[tid];
    __syncthreads();

    // ---- phase 1: fused matvecs (query / cand_key / cand_value) ----
    const int d    = tid & (BD-1);   // output dim
    const int h    = tid >> 7;       // row half (0: rows 0-7, 1: rows 8-15)
    const int wave = tid >> 6;
    const int lane = tid & 63;

    float aq[8], ak[8], av[8];
#pragma unroll
    for (int r = 0; r < 8; ++r) { aq[r] = 0.f; ak[r] = 0.f; av[r] = 0.f; }

    // k in [0,128): signal feeds all three heads
    for (int kk = 0; kk < BD; kk += 4) {
        float wq0 = w_rq[(kk+0)*BD + d], wq1 = w_rq[(kk+1)*BD + d],
              wq2 = w_rq[(kk+2)*BD + d], wq3 = w_rq[(kk+3)*BD + d];
        float wk0 = w_key[(kk+0)*BD + d], wk1 = w_key[(kk+1)*BD + d],
              wk2 = w_key[(kk+2)*BD + d], wk3 = w_key[(kk+3)*BD + d];
        float wv0 = w_val[(kk+0)*BD + d], wv1 = w_val[(kk+1)*BD + d],
              wv2 = w_val[(kk+2)*BD + d], wv3 = w_val[(kk+3)*BD + d];
#pragma unroll
        for (int r = 0; r < 8; ++r) {
            const float4 s4 = *(const float4*)&sig_s[h*8 + r][kk];
            aq[r] = fmaf(s4.w, wq3, fmaf(s4.z, wq2, fmaf(s4.y, wq1, fmaf(s4.x, wq0, aq[r]))));
            ak[r] = fmaf(s4.w, wk3, fmaf(s4.z, wk2, fmaf(s4.y, wk1, fmaf(s4.x, wk0, ak[r]))));
            av[r] = fmaf(s4.w, wv3, fmaf(s4.z, wv2, fmaf(s4.y, wv1, fmaf(s4.x, wv0, av[r]))));
        }
    }
    // k in [128,256): previous feeds query; hidden feeds key/value
    for (int kk = 0; kk < BD; kk += 4) {
        const int k = kk + BD;
        float wq0 = w_rq[(k+0)*BD + d], wq1 = w_rq[(k+1)*BD + d],
              wq2 = w_rq[(k+2)*BD + d], wq3 = w_rq[(k+3)*BD + d];
        float wk0 = w_key[(k+0)*BD + d], wk1 = w_key[(k+1)*BD + d],
              wk2 = w_key[(k+2)*BD + d], wk3 = w_key[(k+3)*BD + d];
        float wv0 = w_val[(k+0)*BD + d], wv1 = w_val[(k+1)*BD + d],
              wv2 = w_val[(k+2)*BD + d], wv3 = w_val[(k+3)*BD + d];
#pragma unroll
        for (int r = 0; r < 8; ++r) {
            const float4 p4 = *(const float4*)&prv_s[h*8 + r][kk];
            const float4 h4 = *(const float4*)&hid_s[h*8 + r][kk];
            aq[r] = fmaf(p4.w, wq3, fmaf(p4.z, wq2, fmaf(p4.y, wq1, fmaf(p4.x, wq0, aq[r]))));
            ak[r] = fmaf(h4.w, wk3, fmaf(h4.z, wk2, fmaf(h4.y, wk1, fmaf(h4.x, wk0, ak[r]))));
            av[r] = fmaf(h4.w, wv3, fmaf(h4.z, wv2, fmaf(h4.y, wv1, fmaf(h4.x, wv0, av[r]))));
        }
    }

    const float bk = b_key[d], bv = b_val[d];
    float ckr[8], cvr[8], q2[8], c2[8];
#pragma unroll
    for (int r = 0; r < 8; ++r) {
        ckr[r] = tanhf(ak[r] + bk);
        cvr[r] = tanhf(av[r] + bv);
        q2[r]  = aq[r] * aq[r];
        c2[r]  = ckr[r] * ckr[r];
    }
#pragma unroll
    for (int off = 32; off > 0; off >>= 1) {
#pragma unroll
        for (int r = 0; r < 8; ++r) {
            q2[r] += __shfl_xor(q2[r], off);
            c2[r] += __shfl_xor(c2[r], off);
        }
    }
    if (lane == 0) {
#pragma unroll
        for (int r = 0; r < 8; ++r) { red_s[wave][r][0] = q2[r]; red_s[wave][r][1] = c2[r]; }
    }
    __syncthreads();
#pragma unroll
    for (int r = 0; r < 8; ++r) {
        float sq = red_s[h*2][r][0] + red_s[h*2+1][r][0];
        float sc = red_s[h*2][r][1] + red_s[h*2+1][r][1];
        float qi = 1.0f / fmaxf(sqrtf(sq), 1e-6f);
        q_s[h*8 + r][d]  = aq[r] * qi;     // normalized query
        ck_s[h*8 + r][d] = ckr[r];         // raw candidate key
        cv_s[h*8 + r][d] = cvr[r];         // raw candidate value
        if (d == 0) ckinv_s[h*8 + r] = 1.0f / fmaxf(sqrtf(sc), 1e-6f);
    }
    __syncthreads();

    // ---- phase 2: one wave per row, slot logic ----
    const float bmix = b_mix[0], bwr = b_wr[0], bpe = b_pe[0], bmg = b_mg[0];

    for (int rr = 0; rr < 4; ++rr) {
        const int r = wave*4 + rr;
        const size_t row = (size_t)row0 + r;
        const size_t kvb = row * (size_t)(NS*BD);
        const float2* kp = (const float2*)(g_keys + kvb);
        const float2* vp = (const float2*)(g_vals + kvb);
        float2 kf[NS], vf[NS];
#pragma unroll
        for (int n = 0; n < NS; ++n) { kf[n] = kp[n*64 + lane]; vf[n] = vp[n*64 + lane]; }
        const float2 qv  = *(const float2*)&q_s[r][2*lane];
        const float2 cki = *(const float2*)&ck_s[r][2*lane];
        const float2 cvi = *(const float2*)&cv_s[r][2*lane];
        const float ckinv = ckinv_s[r];

        float cs[NS], sim[NS];
#pragma unroll
        for (int n = 0; n < NS; ++n) {
            float pk = kf[n].x*kf[n].x + kf[n].y*kf[n].y;
            float pq = qv.x*kf[n].x + qv.y*kf[n].y;
            float pc = cki.x*kf[n].x + cki.y*kf[n].y;
#pragma unroll
            for (int off = 32; off > 0; off >>= 1) {
                pk += __shfl_xor(pk, off);
                pq += __shfl_xor(pq, off);
                pc += __shfl_xor(pc, off);
            }
            float ki = 1.0f / fmaxf(sqrtf(pk), 1e-6f);
            cs[n]  = pq * ki;           // q_hat . k_hat
            sim[n] = pc * ki * ckinv;   // ck_hat . k_hat
        }

        // scalar heads: read_mix (sp), write/persist/merge (joined)
        float pmix = 0.f, pwr = 0.f, ppe = 0.f, pmg = 0.f;
#pragma unroll
        for (int j = 0; j < 4; ++j) {
            int k = lane + j*64;
            float spv = (k < BD) ? sig_s[r][k] : prv_s[r][k-BD];
            float jnv = (k < BD) ? sig_s[r][k] : hid_s[r][k-BD];
            pmix = fmaf(spv, wmix_s[k], pmix);
            pwr  = fmaf(jnv, wwr_s[k],  pwr);
            ppe  = fmaf(jnv, wpe_s[k],  ppe);
            pmg  = fmaf(jnv, wmg_s[k],  pmg);
        }
#pragma unroll
        for (int off = 32; off > 0; off >>= 1) {
            pmix += __shfl_xor(pmix, off);
            pwr  += __shfl_xor(pwr,  off);
            ppe  += __shfl_xor(ppe,  off);
            pmg  += __shfl_xor(pmg,  off);
        }
        const float mix   = sigm(pmix + bmix);
        const float wsv   = sigm(pwr + bwr);
        const float pev   = sigm(ppe + bpe);
        const float mglin = pmg + bmg;

        // content softmax
        float mC = cs[0];
#pragma unroll
        for (int n = 1; n < NS; ++n) mC = fmaxf(mC, cs[n]);
        float eC[NS], sC = 0.f;
#pragma unroll
        for (int n = 0; n < NS; ++n) { eC[n] = __expf((cs[n]-mC)*4.0f); sC += eC[n]; }
        // persistent softmax
        float psc[NS]; float mP = -1e30f;
#pragma unroll
        for (int n = 0; n < NS; ++n) {
            psc[n] = fmaf(2.4f, str_s[r*NS+n], 0.6f*(1.0f - age_s[r*NS+n]));
            mP = fmaxf(mP, psc[n]);
        }
        float eP[NS], sP = 0.f;
#pragma unroll
        for (int n = 0; n < NS; ++n) { eP[n] = __expf((psc[n]-mP)*4.0f); sP += eP[n]; }
        const float icS = 1.0f/sC, ipS = 1.0f/sP;

        float2 cr = make_float2(0.f, 0.f), prd = make_float2(0.f, 0.f);
#pragma unroll
        for (int n = 0; n < NS; ++n) {
            float wc = eC[n]*icS, wp = eP[n]*ipS;
            cr.x  = fmaf(wc, vf[n].x, cr.x);  cr.y  = fmaf(wc, vf[n].y, cr.y);
            prd.x = fmaf(wp, vf[n].x, prd.x); prd.y = fmaf(wp, vf[n].y, prd.y);
        }
        float2 mr;
        mr.x = mix*cr.x + (1.0f-mix)*prd.x;
        mr.y = mix*cr.y + (1.0f-mix)*prd.y;
        ((float2*)(o_read + row*BD))[lane] = mr;

        // top-3 of sim (ties -> lowest index, matching lax.top_k)
        float tmp[NS];
#pragma unroll
        for (int n = 0; n < NS; ++n) tmp[n] = sim[n];
        float tv0 = -1e30f, tv1 = -1e30f, tv2 = -1e30f;
        int   ti0 = 0, ti1 = 0, ti2 = 0;
#pragma unroll
        for (int n = 0; n < NS; ++n) if (tmp[n] > tv0) { tv0 = tmp[n]; ti0 = n; }
        tmp[ti0] = -1e30f;
#pragma unroll
        for (int n = 0; n < NS; ++n) if (tmp[n] > tv1) { tv1 = tmp[n]; ti1 = n; }
        tmp[ti1] = -1e30f;
#pragma unroll
        for (int n = 0; n < NS; ++n) if (tmp[n] > tv2) { tv2 = tmp[n]; ti2 = n; }

        // replace argmax (first max)
        float rm = -1e30f; int ri = 0;
#pragma unroll
        for (int n = 0; n < NS; ++n) {
            float rsv = fmaf(1.2f, age_s[r*NS+n], (1.0f - str_s[r*NS+n])) + 0.5f*(1.0f - sim[n]);
            if (rsv > rm) { rm = rsv; ri = n; }
        }

        const float mpref = sigm(mglin + 2.6f*tv0);
        const bool full  = (tv0 > 0.78f) && (mpref >= 0.55f);
        const bool multi = full && (tv1 > 0.68f);
        const bool part  = (!multi) && (tv0 > 0.64f) && (tv1 > 0.52f);
        const float nov  = fminf(fmaxf(1.0f - tv0, 0.0f), 1.0f);

        float target[NS];
#pragma unroll
        for (int n = 0; n < NS; ++n) target[n] = 0.f;
        if (multi) {
            float e1 = __expf((tv1 - tv0)*4.0f), e2 = __expf((tv2 - tv0)*4.0f);
            float inv = 1.0f/(1.0f + e1 + e2);
            target[ti0] += inv; target[ti1] += e1*inv; target[ti2] += e2*inv;
        } else if (part) {
            float e1 = __expf((tv1 - tv0)*4.0f);
            float inv = 1.0f/(1.0f + e1);
            target[ti0] += inv; target[ti1] += e1*inv;
        } else if (full) {
            target[ti0] = 1.0f;
        } else {
            target[ri] = 1.0f;
        }

        const float scl = multi ? fmaf(0.52f, wsv, 0.16f)
                        : part  ? fmaf(0.62f, wsv, 0.18f)
                                : fmaf(0.80f, wsv, 0.20f);
        const bool  mlike = full || part || multi;
        const float km  = mlike ? fmaf(0.24f, pev, 0.28f) : fmaf(0.16f, pev, 0.78f);
        const float vm  = mlike ? fmaf(0.28f, pev, 0.42f) : fmaf(0.12f, pev, 0.82f);
        const float owc = scl * fmaf(0.45f, nov, 0.55f);
        const float bco = 0.45f + 0.35f*pev + 0.45f*nov + 0.25f*wsv;

        float2* okp = (float2*)(o_keys + kvb);
        float2* ovp = (float2*)(o_vals + kvb);
#pragma unroll
        for (int n = 0; n < NS; ++n) {
            float ow = target[n]*owc;
            float a = ow*km, b2 = ow*vm;
            float2 uk, uv;
            uk.x = fmaf(a,  cki.x - kf[n].x, kf[n].x);
            uk.y = fmaf(a,  cki.y - kf[n].y, kf[n].y);
            uv.x = fmaf(b2, cvi.x - vf[n].x, vf[n].x);
            uv.y = fmaf(b2, cvi.y - vf[n].y, vf[n].y);
            okp[n*64 + lane] = uk;
            ovp[n*64 + lane] = uv;
        }
        if (lane < NS) {
            float ow = target[lane]*owc;
            float us = fminf(fmaxf(fmaf(str_s[r*NS+lane], 0.99f, ow*bco), 0.f), 1.f);
            float ua = fminf(fmaxf((age_s[r*NS+lane] + 0.02f)*(1.0f - ow), 0.f), 1.f);
            o_str[row*NS + lane] = us;
            o_age[row*NS + lane] = ua;
        }
    }
}

extern "C" void kernel_launch(void* const* d_in, const int* in_sizes, int n_in,
                              void* d_out, int out_size, void* d_ws, size_t ws_size,
                              hipStream_t stream) {
    const float* g_signal = (const float*)d_in[0];
    const float* g_prev   = (const float*)d_in[1];
    const float* g_hidden = (const float*)d_in[2];
    const float* g_keys   = (const float*)d_in[3];
    const float* g_vals   = (const float*)d_in[4];
    const float* g_str    = (const float*)d_in[5];
    const float* g_age    = (const float*)d_in[6];
    const float* w_rq     = (const float*)d_in[7];
    const float* w_mix    = (const float*)d_in[8];
    const float* b_mix    = (const float*)d_in[9];
    const float* w_key    = (const float*)d_in[10];
    const float* b_key    = (const float*)d_in[11];
    const float* w_val    = (const float*)d_in[12];
    const float* b_val    = (const float*)d_in[13];
    const float* w_wr     = (const float*)d_in[14];
    const float* b_wr     = (const float*)d_in[15];
    const float* w_pe     = (const float*)d_in[16];
    const float* b_pe     = (const float*)d_in[17];
    const float* w_mg     = (const float*)d_in[18];
    const float* b_mg     = (const float*)d_in[19];

    const size_t B = (size_t)in_sizes[0] / BD;   // 32768
    float* out   = (float*)d_out;
    float* o_read = out;
    float* o_keys = o_read + B*BD;
    float* o_vals = o_keys + B*NS*BD;
    float* o_str  = o_vals + B*NS*BD;
    float* o_age  = o_str  + B*NS;

    const int blocks = (int)(B / ROWS);
    sbcore_kernel<<<dim3(blocks), dim3(BLOCK), 0, stream>>>(
        g_signal, g_prev, g_hidden, g_keys, g_vals, g_str, g_age,
        w_rq, w_mix, b_mix, w_key, b_key, w_val, b_val,
        w_wr, b_wr, w_pe, b_pe, w_mg, b_mg,
        o_read, o_keys, o_vals, o_str, o_age);
}